// Round 4
// baseline (222.494 us; speedup 1.0000x reference)
//
#include <hip/hip_runtime.h>
#include <math.h>

namespace {

constexpr int B_   = 8;
constexpr int S_   = 8192;
constexpr int NROW = B_ * S_;      // 65536
constexpr int MC   = 48;           // model channels
constexpr int OF   = 88;           // output features
constexpr int KW   = 31;           // window
constexpr int F1   = 229;
constexpr int F2   = 136;          // 88 + 48
constexpr int X2ST = 144;          // padded x2 row stride (576 B = 9 cache lines)

typedef __attribute__((ext_vector_type(8))) short bf16x8;
typedef __attribute__((ext_vector_type(4))) float f32x4;

__device__ inline unsigned short f2bf(float v) {
    unsigned u = __float_as_uint(v);
    unsigned r = (u + 0x7FFFu + ((u >> 16) & 1u)) >> 16;
    return (unsigned short)r;
}
__device__ inline float bf2f(unsigned short b) {
    return __uint_as_float((unsigned)b << 16);
}
__device__ inline unsigned pack2(unsigned short a, unsigned short b) {
    return (unsigned)a | ((unsigned)b << 16);
}

// ---- W prep: q,k,v stacked (144 rows) -> bf16 hi/lo, chunk-major
// layout: out[chunk][plane][oc][56]; plane-stride 8192, chunk-stride 16384
__global__ void wprep_kernel(const float* __restrict__ Wq,
                             const float* __restrict__ Wk,
                             const float* __restrict__ Wv,
                             int K, int nch, unsigned short* __restrict__ out) {
    int idx = blockIdx.x * 256 + threadIdx.x;
    int kpad = nch * 32;
    int total = 144 * kpad;
    if (idx >= total) return;
    int oc = idx / kpad;
    int kg = idx - oc * kpad;
    int c  = kg >> 5, kk = kg & 31;
    float val = 0.f;
    if (kg < K) {
        const float* W = (oc < 48) ? Wq : (oc < 96 ? Wk : Wv);
        int ocl = (oc < 48) ? oc : (oc < 96 ? oc - 48 : oc - 96);
        val = W[ocl * K + kg];
    }
    unsigned short h = f2bf(val);
    unsigned short l = f2bf(val - bf2f(h));
    size_t base = (size_t)c * 16384 + (size_t)oc * 56 + kk;
    out[base]        = h;
    out[base + 8192] = l;
}

// ---- Wo/Wf prep: transpose to [96 n][64 k] bf16, hi plane then lo plane ----
__global__ void woprep_kernel(const float* __restrict__ W,  // [88][48]
                              unsigned short* __restrict__ out) {
    int idx = blockIdx.x * 256 + threadIdx.x;   // 96*64
    if (idx >= 96 * 64) return;
    int n = idx >> 6, k = idx & 63;
    float val = (n < OF && k < MC) ? W[n * MC + k] : 0.f;
    unsigned short h = f2bf(val);
    unsigned short l = f2bf(val - bf2f(h));
    out[idx]        = h;
    out[6144 + idx] = l;
}

// ===== fused proj(MFMA) + windowed attention + LN + out-linear(MFMA) ========
// 64 output rows/block, 96 halo rows, 512 threads (8 waves).
template<int K, int XST, int NCH, bool FIRST>
__global__ __launch_bounds__(512) void fused_kernel(
    const float* __restrict__ x,             // [NROW][XST]
    const unsigned short* __restrict__ wbuf, // qkv W chunks [NCH][2][144][56]
    const float* __restrict__ rel,           // [48][31]
    const float* __restrict__ lng,
    const float* __restrict__ lnb,
    const unsigned short* __restrict__ wop,  // out-linear W [2][96][64]
    const float* __restrict__ bo,            // [88]
    float* __restrict__ pred,                // [NROW][88]
    float* __restrict__ attn_out,            // [NROW][8][31]  (FIRST)
    float* __restrict__ x2)                  // [NROW][144]    (FIRST)
{
    __shared__ __attribute__((aligned(16))) unsigned short Ah[96 * 40];
    __shared__ __attribute__((aligned(16))) unsigned short Al[96 * 40];
    __shared__ __attribute__((aligned(16))) unsigned short Bblk[16384];
    __shared__ __attribute__((aligned(16))) float kvT[2 * 48 * 102]; // [k|v][col][102]
    __shared__ __attribute__((aligned(16))) float qs[64 * 52];
    __shared__ __attribute__((aligned(16))) float relT[31 * 52];
    __shared__ __attribute__((aligned(16))) unsigned short lnbuf[2][64 * 48 + 64];
    __shared__ float bosL[96];
    __shared__ float lngs[48], lnbs[48];

    const int tid  = threadIdx.x;
    const int bid  = ((blockIdx.x & 7) << 7) + (blockIdx.x >> 3);  // XCD swizzle
    const int bb   = bid >> 7;
    const int st0  = (bid & 127) * 64;
    const size_t base = (size_t)bb * S_;

    // one-time small staging (regions untouched by the proj loop)
    for (int idx = tid; idx < MC * KW; idx += 512) {
        int c = idx / KW, j = idx - c * KW;
        relT[j * 52 + c] = rel[idx];
    }
    if (tid < 96) bosL[tid] = (tid < OF) ? bo[tid] : 0.f;
    if (tid >= 128 && tid < 176) {
        lngs[tid - 128] = lng[tid - 128];
        lnbs[tid - 128] = lnb[tid - 128];
    }
    if (tid >= 192 && tid < 256) {          // zero lnbuf tail pad (MFMA overread)
        lnbuf[0][64 * 48 + tid - 192] = 0;
        lnbuf[1][64 * 48 + tid - 192] = 0;
    }

    const int l   = tid & 63;
    const int w   = tid >> 6;
    const int lr  = l & 15;
    const int lk8 = (l >> 4) * 8;

    // ---------------- proj phase: 96 halo rows x 144 (q,k,v) ----------------
    f32x4 acc[9];
    #pragma unroll
    for (int nt = 0; nt < 9; ++nt) acc[nt] = f32x4{0.f, 0.f, 0.f, 0.f};

    for (int c = 0; c < NCH; ++c) {
        if (c) __syncthreads();
        {   // stage W chunk (32 KB)
            const uint4* src = (const uint4*)(wbuf + (size_t)c * 16384);
            uint4* dst = (uint4*)Bblk;
            #pragma unroll
            for (int i = 0; i < 4; ++i) dst[tid + 512 * i] = src[tid + 512 * i];
        }
        // stage x chunk: 96 rows x 32 k -> bf16 hi/lo (OOB rows/k -> 0)
        #pragma unroll
        for (int i = 0; i < 3; ++i) {
            int idx = tid + 512 * i;         // 0..1535
            int r   = idx >> 4;              // 0..95
            int k2  = (idx & 15) * 2;
            int inrow = st0 - 16 + r;
            int kg  = c * 32 + k2;
            bool rok = (unsigned)inrow < (unsigned)S_;
            float v0 = (rok && kg     < K) ? x[(base + inrow) * (size_t)XST + kg]     : 0.f;
            float v1 = (rok && kg + 1 < K) ? x[(base + inrow) * (size_t)XST + kg + 1] : 0.f;
            unsigned short h0 = f2bf(v0), h1 = f2bf(v1);
            unsigned short l0 = f2bf(v0 - bf2f(h0));
            unsigned short l1 = f2bf(v1 - bf2f(h1));
            *(unsigned*)&Ah[r * 40 + k2] = pack2(h0, h1);
            *(unsigned*)&Al[r * 40 + k2] = pack2(l0, l1);
        }
        __syncthreads();
        if (w < 6) {
            bf16x8 ah = *(const bf16x8*)&Ah[(16 * w + lr) * 40 + lk8];
            bf16x8 al = *(const bf16x8*)&Al[(16 * w + lr) * 40 + lk8];
            #pragma unroll
            for (int nt = 0; nt < 9; ++nt) {
                int bcol = nt * 16 + lr;
                bf16x8 bh = *(const bf16x8*)&Bblk[bcol * 56 + lk8];
                bf16x8 bl = *(const bf16x8*)&Bblk[8192 + bcol * 56 + lk8];
                acc[nt] = __builtin_amdgcn_mfma_f32_16x16x32_bf16(ah, bh, acc[nt], 0, 0, 0);
                acc[nt] = __builtin_amdgcn_mfma_f32_16x16x32_bf16(ah, bl, acc[nt], 0, 0, 0);
                acc[nt] = __builtin_amdgcn_mfma_f32_16x16x32_bf16(al, bh, acc[nt], 0, 0, 0);
            }
        }
    }
    // epilogue -> LDS: q (rows 16..80) and transposed k/v (all 96 halo rows)
    if (w < 6) {
        const int hb = 16 * w + ((l >> 4) << 2);
        #pragma unroll
        for (int nt = 3; nt < 9; ++nt) {
            float* dT = (nt < 6) ? kvT : (kvT + 48 * 102);
            int col = (nt - (nt < 6 ? 3 : 6)) * 16 + lr;
            #pragma unroll
            for (int rg = 0; rg < 4; ++rg)
                dT[col * 102 + hb + rg] = acc[nt][rg];
        }
        if (w >= 1 && w <= 4) {
            #pragma unroll
            for (int nt = 0; nt < 3; ++nt) {
                int col = nt * 16 + lr;
                #pragma unroll
                for (int rg = 0; rg < 4; ++rg)
                    qs[(hb - 16 + rg) * 52 + col] = acc[nt][rg];
            }
        }
    }
    __syncthreads();

    // ---------------- attention phase: thread = (row rl, group g) -----------
    const int rl  = tid >> 3;
    const int g   = tid & 7;
    const int ch0 = g * 6;
    const size_t grow = base + st0 + rl;

    float2 q01 = *(const float2*)&qs[rl * 52 + ch0];
    float2 q23 = *(const float2*)&qs[rl * 52 + ch0 + 2];
    float2 q45 = *(const float2*)&qs[rl * 52 + ch0 + 4];

    const float* kT = kvT + rl + 1;        // halo row = rl + 1 + j
    const float* vT = kvT + 48 * 102 + rl + 1;

    float e[KW];
    float mx = -1e30f;
    #pragma unroll
    for (int j = 0; j < KW; ++j) {
        const float* rp = &relT[j * 52 + ch0];
        float2 r01 = *(const float2*)rp;
        float2 r23 = *(const float2*)(rp + 2);
        float2 r45 = *(const float2*)(rp + 4);
        float s = q01.x * (kT[(ch0 + 0) * 102 + j] + r01.x)
                + q01.y * (kT[(ch0 + 1) * 102 + j] + r01.y)
                + q23.x * (kT[(ch0 + 2) * 102 + j] + r23.x)
                + q23.y * (kT[(ch0 + 3) * 102 + j] + r23.y)
                + q45.x * (kT[(ch0 + 4) * 102 + j] + r45.x)
                + q45.y * (kT[(ch0 + 5) * 102 + j] + r45.y);
        e[j] = s;
        mx = fmaxf(mx, s);
    }
    float den = 0.f;
    #pragma unroll
    for (int j = 0; j < KW; ++j) { float t = __expf(e[j] - mx); e[j] = t; den += t; }
    float rden = 1.f / den;

    float o0 = 0.f, o1 = 0.f, o2 = 0.f, o3 = 0.f, o4 = 0.f, o5 = 0.f;
    #pragma unroll
    for (int j = 0; j < KW; ++j) {
        float aw = e[j] * rden;
        if constexpr (FIRST) attn_out[(grow * 8 + g) * KW + j] = aw;
        o0 += aw * vT[(ch0 + 0) * 102 + j];
        o1 += aw * vT[(ch0 + 1) * 102 + j];
        o2 += aw * vT[(ch0 + 2) * 102 + j];
        o3 += aw * vT[(ch0 + 3) * 102 + j];
        o4 += aw * vT[(ch0 + 4) * 102 + j];
        o5 += aw * vT[(ch0 + 5) * 102 + j];
    }

    // LayerNorm across 48 channels (8 lanes x 6)
    float sum = o0 + o1 + o2 + o3 + o4 + o5;
    sum += __shfl_xor(sum, 1, 8);
    sum += __shfl_xor(sum, 2, 8);
    sum += __shfl_xor(sum, 4, 8);
    float mu = sum * (1.f / 48.f);
    float d0 = o0 - mu, d1 = o1 - mu, d2 = o2 - mu, d3 = o3 - mu, d4 = o4 - mu, d5 = o5 - mu;
    float vr = d0*d0 + d1*d1 + d2*d2 + d3*d3 + d4*d4 + d5*d5;
    vr += __shfl_xor(vr, 1, 8);
    vr += __shfl_xor(vr, 2, 8);
    vr += __shfl_xor(vr, 4, 8);
    float rstd = rsqrtf(vr * (1.f / 48.f) + 1e-5f);
    float y[6];
    y[0] = d0 * rstd * lngs[ch0]     + lnbs[ch0];
    y[1] = d1 * rstd * lngs[ch0 + 1] + lnbs[ch0 + 1];
    y[2] = d2 * rstd * lngs[ch0 + 2] + lnbs[ch0 + 2];
    y[3] = d3 * rstd * lngs[ch0 + 3] + lnbs[ch0 + 3];
    y[4] = d4 * rstd * lngs[ch0 + 4] + lnbs[ch0 + 4];
    y[5] = d5 * rstd * lngs[ch0 + 5] + lnbs[ch0 + 5];

    {   // stage y as bf16 hi/lo for the out-linear MFMA
        unsigned short h[6], lo[6];
        #pragma unroll
        for (int c = 0; c < 6; ++c) {
            h[c]  = f2bf(y[c]);
            lo[c] = f2bf(y[c] - bf2f(h[c]));
        }
        unsigned* ph = (unsigned*)&lnbuf[0][rl * 48 + ch0];
        unsigned* pl = (unsigned*)&lnbuf[1][rl * 48 + ch0];
        ph[0] = pack2(h[0], h[1]);   ph[1] = pack2(h[2], h[3]);   ph[2] = pack2(h[4], h[5]);
        pl[0] = pack2(lo[0], lo[1]); pl[1] = pack2(lo[2], lo[3]); pl[2] = pack2(lo[4], lo[5]);
    }
    if constexpr (FIRST) {
        float* xp = x2 + grow * X2ST + OF + ch0;
        *(float2*)(xp)     = float2{y[0], y[1]};
        *(float2*)(xp + 2) = float2{y[2], y[3]};
        *(float2*)(xp + 4) = float2{y[4], y[5]};
    }
    __syncthreads();

    // ---------------- out-linear MFMA: [64x48] x [48x88] + sigmoid ----------
    const int m  = w & 3;        // row-tile
    const int ng = w >> 2;       // col-tile group (3 tiles each)

    bf16x8 bh[3][2], bl[3][2];
    #pragma unroll
    for (int nt = 0; nt < 3; ++nt) {
        int ncol = (ng * 3 + nt) * 16 + lr;
        #pragma unroll
        for (int kc = 0; kc < 2; ++kc) {
            size_t boff = (size_t)ncol * 64 + kc * 32 + lk8;
            bh[nt][kc] = *(const bf16x8*)&wop[boff];
            bl[nt][kc] = *(const bf16x8*)&wop[6144 + boff];
        }
    }
    const int arow = m * 16 + lr;
    bf16x8 ah0 = *(const bf16x8*)&lnbuf[0][arow * 48 + lk8];
    bf16x8 al0 = *(const bf16x8*)&lnbuf[1][arow * 48 + lk8];
    bf16x8 ah1 = *(const bf16x8*)&lnbuf[0][arow * 48 + 32 + lk8];
    bf16x8 al1 = *(const bf16x8*)&lnbuf[1][arow * 48 + 32 + lk8];

    f32x4 oacc[3];
    #pragma unroll
    for (int nt = 0; nt < 3; ++nt) oacc[nt] = f32x4{0.f, 0.f, 0.f, 0.f};
    #pragma unroll
    for (int nt = 0; nt < 3; ++nt) {
        oacc[nt] = __builtin_amdgcn_mfma_f32_16x16x32_bf16(ah0, bh[nt][0], oacc[nt], 0, 0, 0);
        oacc[nt] = __builtin_amdgcn_mfma_f32_16x16x32_bf16(ah0, bl[nt][0], oacc[nt], 0, 0, 0);
        oacc[nt] = __builtin_amdgcn_mfma_f32_16x16x32_bf16(al0, bh[nt][0], oacc[nt], 0, 0, 0);
        oacc[nt] = __builtin_amdgcn_mfma_f32_16x16x32_bf16(ah1, bh[nt][1], oacc[nt], 0, 0, 0);
        oacc[nt] = __builtin_amdgcn_mfma_f32_16x16x32_bf16(ah1, bl[nt][1], oacc[nt], 0, 0, 0);
        oacc[nt] = __builtin_amdgcn_mfma_f32_16x16x32_bf16(al1, bh[nt][1], oacc[nt], 0, 0, 0);
    }

    const int rowo = st0 + m * 16 + ((l >> 4) << 2);
    #pragma unroll
    for (int nt = 0; nt < 3; ++nt) {
        int col = (ng * 3 + nt) * 16 + lr;
        if (col < OF) {
            float bias = bosL[col];
            #pragma unroll
            for (int rg = 0; rg < 4; ++rg) {
                float s  = oacc[nt][rg] + bias;
                float sg = 1.f / (1.f + __expf(-s));
                size_t row = base + rowo + rg;
                pred[row * OF + col] = sg;
                if constexpr (FIRST) x2[row * X2ST + col] = sg;
            }
        }
    }
}

} // namespace

extern "C" void kernel_launch(void* const* d_in, const int* in_sizes, int n_in,
                              void* d_out, int out_size, void* d_ws, size_t ws_size,
                              hipStream_t stream) {
    const float* spec = (const float*)d_in[0];
    const float* Wq1  = (const float*)d_in[1];
    const float* Wk1  = (const float*)d_in[2];
    const float* Wv1  = (const float*)d_in[3];
    const float* rel1 = (const float*)d_in[4];
    const float* ln1g = (const float*)d_in[5];
    const float* ln1b = (const float*)d_in[6];
    const float* Wo   = (const float*)d_in[7];
    const float* bo   = (const float*)d_in[8];
    const float* Wq2  = (const float*)d_in[9];
    const float* Wk2  = (const float*)d_in[10];
    const float* Wv2  = (const float*)d_in[11];
    const float* rel2 = (const float*)d_in[12];
    const float* ln2g = (const float*)d_in[13];
    const float* ln2b = (const float*)d_in[14];
    const float* Wf   = (const float*)d_in[15];
    const float* bf_  = (const float*)d_in[16];

    float* outf   = (float*)d_out;
    float* frame  = outf;
    float* onset  = outf + (size_t)NROW * OF;
    float* attn_a = outf + (size_t)2 * NROW * OF;

    float* wsf = (float*)d_ws;
    float* x2 = wsf;                                      // [NROW][144]
    unsigned short* wbuf1 = (unsigned short*)(x2 + (size_t)NROW * X2ST);
    unsigned short* wbuf2 = wbuf1 + (size_t)8 * 16384;
    unsigned short* woP1  = wbuf2 + (size_t)5 * 16384;    // [2][96][64]
    unsigned short* woP2  = woP1 + 2 * 6144;

    wprep_kernel<<<(144 * 8 * 32 + 255) / 256, 256, 0, stream>>>(Wq1, Wk1, Wv1, F1, 8, wbuf1);
    wprep_kernel<<<(144 * 5 * 32 + 255) / 256, 256, 0, stream>>>(Wq2, Wk2, Wv2, F2, 5, wbuf2);
    woprep_kernel<<<24, 256, 0, stream>>>(Wo, woP1);
    woprep_kernel<<<24, 256, 0, stream>>>(Wf, woP2);

    fused_kernel<F1, F1, 8, true><<<NROW / 64, 512, 0, stream>>>(
        spec, wbuf1, rel1, ln1g, ln1b, woP1, bo, onset, attn_a, x2);
    fused_kernel<F2, X2ST, 5, false><<<NROW / 64, 512, 0, stream>>>(
        x2, wbuf2, rel2, ln2g, ln2b, woP2, bf_, frame, nullptr, nullptr);
}

// Round 5
// 184.318 us; speedup vs baseline: 1.2071x; 1.2071x over previous
//
#include <hip/hip_runtime.h>
#include <math.h>

namespace {

constexpr int B_   = 8;
constexpr int S_   = 8192;
constexpr int NROW = B_ * S_;      // 65536
constexpr int MC   = 48;           // model channels
constexpr int OF   = 88;           // output features
constexpr int KW   = 31;           // window
constexpr int F1   = 229;
constexpr int F2   = 136;          // 88 + 48

typedef __attribute__((ext_vector_type(8))) short bf16x8;
typedef __attribute__((ext_vector_type(4))) float f32x4;

__device__ inline unsigned short f2bf(float v) {
    unsigned u = __float_as_uint(v);
    unsigned r = (u + 0x7FFFu + ((u >> 16) & 1u)) >> 16;
    return (unsigned short)r;
}
__device__ inline float bf2f(unsigned short b) {
    return __uint_as_float((unsigned)b << 16);
}
__device__ inline unsigned pack2(unsigned short a, unsigned short b) {
    return (unsigned)a | ((unsigned)b << 16);
}

// ---- W prep: q,k,v stacked (144 rows) -> bf16 hi/lo, chunk-major -----------
__global__ void wprep_kernel(const float* __restrict__ Wq,
                             const float* __restrict__ Wk,
                             const float* __restrict__ Wv,
                             int K, int nch, unsigned short* __restrict__ out) {
    int idx = blockIdx.x * 256 + threadIdx.x;
    int kpad = nch * 32;
    int total = 144 * kpad;
    if (idx >= total) return;
    int oc = idx / kpad;
    int kg = idx - oc * kpad;
    int c  = kg >> 5, kk = kg & 31;
    float val = 0.f;
    if (kg < K) {
        const float* W = (oc < 48) ? Wq : (oc < 96 ? Wk : Wv);
        int ocl = (oc < 48) ? oc : (oc < 96 ? oc - 48 : oc - 96);
        val = W[ocl * K + kg];
    }
    unsigned short h = f2bf(val);
    unsigned short l = f2bf(val - bf2f(h));
    size_t base = (size_t)c * 16384 + (size_t)oc * 56 + kk;
    out[base]        = h;
    out[base + 8192] = l;
}

// ---- Wo/Wf prep: transpose to [96 n][64 k] bf16, hi plane then lo plane ----
__global__ void woprep_kernel(const float* __restrict__ W,  // [88][48]
                              unsigned short* __restrict__ out) {
    int idx = blockIdx.x * 256 + threadIdx.x;   // 96*64
    if (idx >= 96 * 64) return;
    int n = idx >> 6, k = idx & 63;
    float val = (n < OF && k < MC) ? W[n * MC + k] : 0.f;
    unsigned short h = f2bf(val);
    unsigned short l = f2bf(val - bf2f(h));
    out[idx]        = h;
    out[6144 + idx] = l;
}

// ---- projection GEMM via MFMA, 3-term bf16 hi/lo split (round-3 proven) ----
template<int K, int NCH>
__global__ __launch_bounds__(256) void proj_mfma(
    const float* __restrict__ x,
    const unsigned short* __restrict__ wbuf,
    float* __restrict__ qo, float* __restrict__ ko, float* __restrict__ vo)
{
    __shared__ __attribute__((aligned(16))) unsigned short Ah[64 * 56];
    __shared__ __attribute__((aligned(16))) unsigned short Al[64 * 56];
    __shared__ __attribute__((aligned(16))) unsigned short Bblk[16384];

    const int tid  = threadIdx.x;
    const int row0 = blockIdx.x * 64;
    const int lane = tid & 63;
    const int wm   = tid >> 6;

    f32x4 acc[9];
    #pragma unroll
    for (int nt = 0; nt < 9; ++nt) acc[nt] = f32x4{0.f, 0.f, 0.f, 0.f};

    const int arow = wm * 16 + (lane & 15);
    const int ak   = (lane >> 4) * 8;

    for (int c = 0; c < NCH; ++c) {
        {
            const uint4* src = (const uint4*)(wbuf + (size_t)c * 16384);
            uint4* dst = (uint4*)Bblk;
            #pragma unroll
            for (int i = 0; i < 8; ++i)
                dst[tid + 256 * i] = src[tid + 256 * i];
        }
        const int kc = c * 32;
        #pragma unroll
        for (int i = 0; i < 4; ++i) {
            int idx = tid + 256 * i;
            int r   = idx >> 4;
            int k2  = (idx & 15) * 2;
            int kg  = kc + k2;
            const float* xr = x + (size_t)(row0 + r) * K;
            float v0 = (kg     < K) ? xr[kg]     : 0.f;
            float v1 = (kg + 1 < K) ? xr[kg + 1] : 0.f;
            unsigned short h0 = f2bf(v0), h1 = f2bf(v1);
            unsigned short l0 = f2bf(v0 - bf2f(h0));
            unsigned short l1 = f2bf(v1 - bf2f(h1));
            *(unsigned*)&Ah[r * 56 + k2] = pack2(h0, h1);
            *(unsigned*)&Al[r * 56 + k2] = pack2(l0, l1);
        }
        __syncthreads();

        bf16x8 ah = *(const bf16x8*)&Ah[arow * 56 + ak];
        bf16x8 al = *(const bf16x8*)&Al[arow * 56 + ak];
        #pragma unroll
        for (int nt = 0; nt < 9; ++nt) {
            int bcol = nt * 16 + (lane & 15);
            bf16x8 bh = *(const bf16x8*)&Bblk[bcol * 56 + ak];
            bf16x8 bl = *(const bf16x8*)&Bblk[8192 + bcol * 56 + ak];
            acc[nt] = __builtin_amdgcn_mfma_f32_16x16x32_bf16(ah, bh, acc[nt], 0, 0, 0);
            acc[nt] = __builtin_amdgcn_mfma_f32_16x16x32_bf16(ah, bl, acc[nt], 0, 0, 0);
            acc[nt] = __builtin_amdgcn_mfma_f32_16x16x32_bf16(al, bh, acc[nt], 0, 0, 0);
        }
        __syncthreads();
    }

    const int orow = row0 + wm * 16 + ((lane >> 4) << 2);
    const int ocol = lane & 15;
    #pragma unroll
    for (int nt = 0; nt < 9; ++nt) {
        float* dst = (nt < 3) ? qo : (nt < 6 ? ko : vo);
        int oc = (nt % 3) * 16 + ocol;
        #pragma unroll
        for (int rg = 0; rg < 4; ++rg)
            dst[(size_t)(orow + rg) * MC + oc] = acc[nt][rg];
    }
}

// -------- attention + LN + MFMA-linear: 64 rows/block, 2 rows/thread --------
// thread tid = rp*8 + g handles rows (2rp, 2rp+1); rolling k/v/rel reuse
// halves LDS read bytes per output row (the measured bottleneck).
template<bool FIRST>
__global__ __launch_bounds__(256) void attn_kernel(
    const float* __restrict__ qb,     // [NROW][48]
    const float* __restrict__ kb,
    const float* __restrict__ vb,
    const float* __restrict__ rel,    // [48][31]
    const float* __restrict__ lng,
    const float* __restrict__ lnb,
    const unsigned short* __restrict__ wop,  // prepacked WoT hi/lo [2][96][64]
    const float* __restrict__ bo,     // [88]
    float* __restrict__ pred,         // [NROW][88]
    float* __restrict__ attn_out,     // [NROW][8][31]   (FIRST only)
    float* __restrict__ x2)           // [NROW][136]     (FIRST only)
{
    __shared__ __attribute__((aligned(16))) float ks[94 * 52];  // aliased by lnbuf later
    __shared__ __attribute__((aligned(16))) float vs[94 * 52];
    __shared__ __attribute__((aligned(16))) float relT[31 * 52];
    __shared__ float bosL[96];
    __shared__ float lngs[48], lnbs[48];
    // lnbuf alias inside ks (ks dead after pass 1; barrier guards the reuse)
    unsigned short* lnh = (unsigned short*)ks;          // [64*48 + 64]
    unsigned short* lnl = lnh + (64 * 48 + 64);

    const int tid  = threadIdx.x;
    const int bb   = blockIdx.x >> 7;            // 128 tiles per batch
    const int st0  = (blockIdx.x & 127) * 64;
    const size_t base = (size_t)bb * S_;

    // stage k/v halo rows st0-15 .. st0+78 (94 rows x 48 ch, float4)
    for (int idx = tid; idx < 94 * 12; idx += 256) {
        int rr = idx / 12, c4 = idx - rr * 12;
        int si = st0 - 15 + rr;
        float4 kv4 = {0.f, 0.f, 0.f, 0.f}, vv4 = {0.f, 0.f, 0.f, 0.f};
        if (si >= 0 && si < S_) {
            kv4 = *(const float4*)&kb[(base + si) * MC + c4 * 4];
            vv4 = *(const float4*)&vb[(base + si) * MC + c4 * 4];
        }
        *(float4*)&ks[rr * 52 + c4 * 4] = kv4;
        *(float4*)&vs[rr * 52 + c4 * 4] = vv4;
    }
    for (int idx = tid; idx < MC * KW; idx += 256) {
        int c = idx / KW, j = idx - c * KW;
        relT[j * 52 + c] = rel[idx];
    }
    if (tid < 96) bosL[tid] = (tid < OF) ? bo[tid] : 0.f;
    if (tid >= 128 && tid < 176) {
        lngs[tid - 128] = lng[tid - 128];
        lnbs[tid - 128] = lnb[tid - 128];
    }
    __syncthreads();

    const int rp  = tid >> 3;        // row pair 0..31
    const int g   = tid & 7;
    const int ch0 = g * 6;
    const int rA  = 2 * rp;          // local rows rA, rA+1; halo idx = rA + t

    const float* qpA = qb + (base + st0 + rA) * MC + ch0;
    const float* qpB = qpA + MC;
    float2 qa0 = *(const float2*)(qpA);
    float2 qa1 = *(const float2*)(qpA + 2);
    float2 qa2 = *(const float2*)(qpA + 4);
    float2 qb0 = *(const float2*)(qpB);
    float2 qb1 = *(const float2*)(qpB + 2);
    float2 qb2 = *(const float2*)(qpB + 4);

    // pass 1: energies (rolling k/rel shared between the two rows)
    float eA[KW], eB[KW];
    float mxA = -1e30f, mxB = -1e30f;
    float2 rp0, rp1, rp2;            // rel[t-1]
    #pragma unroll
    for (int t = 0; t < 32; ++t) {
        const float* kp = &ks[(rA + t) * 52 + ch0];
        float2 k0 = *(const float2*)(kp);
        float2 k1 = *(const float2*)(kp + 2);
        float2 k2 = *(const float2*)(kp + 4);
        if (t < 31) {
            const float* rr = &relT[t * 52 + ch0];
            float2 r0 = *(const float2*)(rr);
            float2 r1 = *(const float2*)(rr + 2);
            float2 r2 = *(const float2*)(rr + 4);
            float sA = qa0.x * (k0.x + r0.x) + qa0.y * (k0.y + r0.y)
                     + qa1.x * (k1.x + r1.x) + qa1.y * (k1.y + r1.y)
                     + qa2.x * (k2.x + r2.x) + qa2.y * (k2.y + r2.y);
            eA[t] = sA;
            mxA = fmaxf(mxA, sA);
            if (t >= 1) {
                float sB = qb0.x * (k0.x + rp0.x) + qb0.y * (k0.y + rp0.y)
                         + qb1.x * (k1.x + rp1.x) + qb1.y * (k1.y + rp1.y)
                         + qb2.x * (k2.x + rp2.x) + qb2.y * (k2.y + rp2.y);
                eB[t - 1] = sB;
                mxB = fmaxf(mxB, sB);
            }
            rp0 = r0; rp1 = r1; rp2 = r2;
        } else {
            float sB = qb0.x * (k0.x + rp0.x) + qb0.y * (k0.y + rp0.y)
                     + qb1.x * (k1.x + rp1.x) + qb1.y * (k1.y + rp1.y)
                     + qb2.x * (k2.x + rp2.x) + qb2.y * (k2.y + rp2.y);
            eB[30] = sB;
            mxB = fmaxf(mxB, sB);
        }
    }
    float denA = 0.f, denB = 0.f;
    #pragma unroll
    for (int j = 0; j < KW; ++j) {
        float tA = __expf(eA[j] - mxA); eA[j] = tA; denA += tA;
        float tB = __expf(eB[j] - mxB); eB[j] = tB; denB += tB;
    }
    const float rdA = 1.f / denA, rdB = 1.f / denB;

    // pass 2: PV (rolling v shared)
    float oA0=0.f,oA1=0.f,oA2=0.f,oA3=0.f,oA4=0.f,oA5=0.f;
    float oB0=0.f,oB1=0.f,oB2=0.f,oB3=0.f,oB4=0.f,oB5=0.f;
    float* aoutA = FIRST ? (attn_out + ((base + st0 + rA) * 8 + g) * KW) : nullptr;
    #pragma unroll
    for (int t = 0; t < 32; ++t) {
        const float* vp = &vs[(rA + t) * 52 + ch0];
        float2 v0 = *(const float2*)(vp);
        float2 v1 = *(const float2*)(vp + 2);
        float2 v2 = *(const float2*)(vp + 4);
        if (t < 31) {
            float aw = eA[t] * rdA;
            if constexpr (FIRST) aoutA[t] = aw;
            oA0 += aw * v0.x; oA1 += aw * v0.y; oA2 += aw * v1.x;
            oA3 += aw * v1.y; oA4 += aw * v2.x; oA5 += aw * v2.y;
        }
        if (t >= 1) {
            float aw = eB[t - 1] * rdB;
            if constexpr (FIRST) aoutA[8 * KW + t - 1] = aw;
            oB0 += aw * v0.x; oB1 += aw * v0.y; oB2 += aw * v1.x;
            oB3 += aw * v1.y; oB4 += aw * v2.x; oB5 += aw * v2.y;
        }
    }

    // LayerNorm for both rows (reduce over the 8 g-lanes)
    float sA = oA0+oA1+oA2+oA3+oA4+oA5;
    float sB = oB0+oB1+oB2+oB3+oB4+oB5;
    sA += __shfl_xor(sA, 1, 8); sA += __shfl_xor(sA, 2, 8); sA += __shfl_xor(sA, 4, 8);
    sB += __shfl_xor(sB, 1, 8); sB += __shfl_xor(sB, 2, 8); sB += __shfl_xor(sB, 4, 8);
    float muA = sA * (1.f / 48.f), muB = sB * (1.f / 48.f);
    float dA0=oA0-muA,dA1=oA1-muA,dA2=oA2-muA,dA3=oA3-muA,dA4=oA4-muA,dA5=oA5-muA;
    float dB0=oB0-muB,dB1=oB1-muB,dB2=oB2-muB,dB3=oB3-muB,dB4=oB4-muB,dB5=oB5-muB;
    float vA = dA0*dA0+dA1*dA1+dA2*dA2+dA3*dA3+dA4*dA4+dA5*dA5;
    float vB = dB0*dB0+dB1*dB1+dB2*dB2+dB3*dB3+dB4*dB4+dB5*dB5;
    vA += __shfl_xor(vA, 1, 8); vA += __shfl_xor(vA, 2, 8); vA += __shfl_xor(vA, 4, 8);
    vB += __shfl_xor(vB, 1, 8); vB += __shfl_xor(vB, 2, 8); vB += __shfl_xor(vB, 4, 8);
    float rsA = rsqrtf(vA * (1.f / 48.f) + 1e-5f);
    float rsB = rsqrtf(vB * (1.f / 48.f) + 1e-5f);
    float yA[6], yB[6];
    yA[0]=dA0*rsA*lngs[ch0]+lnbs[ch0];     yA[1]=dA1*rsA*lngs[ch0+1]+lnbs[ch0+1];
    yA[2]=dA2*rsA*lngs[ch0+2]+lnbs[ch0+2]; yA[3]=dA3*rsA*lngs[ch0+3]+lnbs[ch0+3];
    yA[4]=dA4*rsA*lngs[ch0+4]+lnbs[ch0+4]; yA[5]=dA5*rsA*lngs[ch0+5]+lnbs[ch0+5];
    yB[0]=dB0*rsB*lngs[ch0]+lnbs[ch0];     yB[1]=dB1*rsB*lngs[ch0+1]+lnbs[ch0+1];
    yB[2]=dB2*rsB*lngs[ch0+2]+lnbs[ch0+2]; yB[3]=dB3*rsB*lngs[ch0+3]+lnbs[ch0+3];
    yB[4]=dB4*rsB*lngs[ch0+4]+lnbs[ch0+4]; yB[5]=dB5*rsB*lngs[ch0+5]+lnbs[ch0+5];

    if constexpr (FIRST) {
        float* xpA = x2 + (base + st0 + rA) * F2 + OF + ch0;
        *(float2*)(xpA)     = float2{yA[0], yA[1]};
        *(float2*)(xpA + 2) = float2{yA[2], yA[3]};
        *(float2*)(xpA + 4) = float2{yA[4], yA[5]};
        float* xpB = xpA + F2;
        *(float2*)(xpB)     = float2{yB[0], yB[1]};
        *(float2*)(xpB + 2) = float2{yB[2], yB[3]};
        *(float2*)(xpB + 4) = float2{yB[4], yB[5]};
    }

    __syncthreads();   // ks dead -> safe to alias with lnbuf

    {   // stage y (both rows) as bf16 hi/lo into the aliased lnbuf
        unsigned short hA[6], lA[6], hB[6], lB[6];
        #pragma unroll
        for (int c = 0; c < 6; ++c) {
            hA[c] = f2bf(yA[c]); lA[c] = f2bf(yA[c] - bf2f(hA[c]));
            hB[c] = f2bf(yB[c]); lB[c] = f2bf(yB[c] - bf2f(hB[c]));
        }
        unsigned* pha = (unsigned*)&lnh[rA * 48 + ch0];
        unsigned* pla = (unsigned*)&lnl[rA * 48 + ch0];
        pha[0] = pack2(hA[0], hA[1]); pha[1] = pack2(hA[2], hA[3]); pha[2] = pack2(hA[4], hA[5]);
        pla[0] = pack2(lA[0], lA[1]); pla[1] = pack2(lA[2], lA[3]); pla[2] = pack2(lA[4], lA[5]);
        unsigned* phb = (unsigned*)&lnh[(rA + 1) * 48 + ch0];
        unsigned* plb = (unsigned*)&lnl[(rA + 1) * 48 + ch0];
        phb[0] = pack2(hB[0], hB[1]); phb[1] = pack2(hB[2], hB[3]); phb[2] = pack2(hB[4], hB[5]);
        plb[0] = pack2(lB[0], lB[1]); plb[1] = pack2(lB[2], lB[3]); plb[2] = pack2(lB[4], lB[5]);
    }
    if (tid < 64) {   // zero tail pad (MFMA k-overread; avoid NaN garbage)
        lnh[64 * 48 + tid] = 0;
        lnl[64 * 48 + tid] = 0;
    }
    __syncthreads();

    // ---- MFMA out-linear: [64x48] x [48x88] + sigmoid; wave w -> row tile --
    const int l   = tid & 63;
    const int w   = tid >> 6;
    const int lr  = l & 15;
    const int lk8 = (l >> 4) * 8;

    const int arow = w * 16 + lr;
    bf16x8 ah0 = *(const bf16x8*)&lnh[arow * 48 + lk8];
    bf16x8 al0 = *(const bf16x8*)&lnl[arow * 48 + lk8];
    bf16x8 ah1 = *(const bf16x8*)&lnh[arow * 48 + 32 + lk8];
    bf16x8 al1 = *(const bf16x8*)&lnl[arow * 48 + 32 + lk8];

    const int rowo = st0 + w * 16 + ((l >> 4) << 2);
    #pragma unroll
    for (int nt = 0; nt < 6; ++nt) {
        int ncol = nt * 16 + lr;
        bf16x8 bh0 = *(const bf16x8*)&wop[(size_t)ncol * 64 + lk8];
        bf16x8 bl0 = *(const bf16x8*)&wop[6144 + (size_t)ncol * 64 + lk8];
        bf16x8 bh1 = *(const bf16x8*)&wop[(size_t)ncol * 64 + 32 + lk8];
        bf16x8 bl1 = *(const bf16x8*)&wop[6144 + (size_t)ncol * 64 + 32 + lk8];
        f32x4 oacc = f32x4{0.f, 0.f, 0.f, 0.f};
        oacc = __builtin_amdgcn_mfma_f32_16x16x32_bf16(ah0, bh0, oacc, 0, 0, 0);
        oacc = __builtin_amdgcn_mfma_f32_16x16x32_bf16(ah0, bl0, oacc, 0, 0, 0);
        oacc = __builtin_amdgcn_mfma_f32_16x16x32_bf16(al0, bh0, oacc, 0, 0, 0);
        oacc = __builtin_amdgcn_mfma_f32_16x16x32_bf16(ah1, bh1, oacc, 0, 0, 0);
        oacc = __builtin_amdgcn_mfma_f32_16x16x32_bf16(ah1, bl1, oacc, 0, 0, 0);
        oacc = __builtin_amdgcn_mfma_f32_16x16x32_bf16(al1, bh1, oacc, 0, 0, 0);
        if (ncol < OF) {
            float bias = bosL[ncol];
            #pragma unroll
            for (int rg = 0; rg < 4; ++rg) {
                float s  = oacc[rg] + bias;
                float sg = 1.f / (1.f + __expf(-s));
                size_t row = base + rowo + rg;
                pred[row * OF + ncol] = sg;
                if constexpr (FIRST) x2[row * F2 + ncol] = sg;
            }
        }
    }
}

} // namespace

extern "C" void kernel_launch(void* const* d_in, const int* in_sizes, int n_in,
                              void* d_out, int out_size, void* d_ws, size_t ws_size,
                              hipStream_t stream) {
    const float* spec = (const float*)d_in[0];
    const float* Wq1  = (const float*)d_in[1];
    const float* Wk1  = (const float*)d_in[2];
    const float* Wv1  = (const float*)d_in[3];
    const float* rel1 = (const float*)d_in[4];
    const float* ln1g = (const float*)d_in[5];
    const float* ln1b = (const float*)d_in[6];
    const float* Wo   = (const float*)d_in[7];
    const float* bo   = (const float*)d_in[8];
    const float* Wq2  = (const float*)d_in[9];
    const float* Wk2  = (const float*)d_in[10];
    const float* Wv2  = (const float*)d_in[11];
    const float* rel2 = (const float*)d_in[12];
    const float* ln2g = (const float*)d_in[13];
    const float* ln2b = (const float*)d_in[14];
    const float* Wf   = (const float*)d_in[15];
    const float* bf_  = (const float*)d_in[16];

    float* outf   = (float*)d_out;
    float* frame  = outf;
    float* onset  = outf + (size_t)NROW * OF;
    float* attn_a = outf + (size_t)2 * NROW * OF;

    float* wsf = (float*)d_ws;
    float* q1 = wsf;
    float* k1 = q1 + (size_t)NROW * MC;
    float* v1 = k1 + (size_t)NROW * MC;
    float* x2 = v1 + (size_t)NROW * MC;                 // [NROW][136]
    unsigned short* wbuf1 = (unsigned short*)(x2 + (size_t)NROW * F2);
    unsigned short* wbuf2 = wbuf1 + (size_t)8 * 16384;
    unsigned short* woP1  = wbuf2 + (size_t)5 * 16384;  // [2][96][64]
    unsigned short* woP2  = woP1 + 2 * 6144;

    wprep_kernel<<<(144 * 8 * 32 + 255) / 256, 256, 0, stream>>>(Wq1, Wk1, Wv1, F1, 8, wbuf1);
    wprep_kernel<<<(144 * 5 * 32 + 255) / 256, 256, 0, stream>>>(Wq2, Wk2, Wv2, F2, 5, wbuf2);
    woprep_kernel<<<24, 256, 0, stream>>>(Wo, woP1);
    woprep_kernel<<<24, 256, 0, stream>>>(Wf, woP2);

    proj_mfma<F1, 8><<<NROW / 64, 256, 0, stream>>>(spec, wbuf1, q1, k1, v1);
    attn_kernel<true><<<NROW / 64, 256, 0, stream>>>(q1, k1, v1, rel1, ln1g, ln1b,
                                                     woP1, bo, onset, attn_a, x2);
    proj_mfma<F2, 5><<<NROW / 64, 256, 0, stream>>>(x2, wbuf2, q1, k1, v1);
    attn_kernel<false><<<NROW / 64, 256, 0, stream>>>(q1, k1, v1, rel2, ln2g, ln2b,
                                                      woP2, bf_, frame, nullptr, nullptr);
}